// Round 1
// baseline (249.403 us; speedup 1.0000x reference)
//
#include <hip/hip_runtime.h>
#include <stdint.h>

typedef __attribute__((ext_vector_type(8))) short short8;
typedef __attribute__((ext_vector_type(4))) float f32x4;
typedef __attribute__((ext_vector_type(2))) float v2f;

#define NCHUNK 32     // 4096 t / 128 t per chunk (2 i-slices per chunk)
#define BROWS  136    // shorts per ldsB row (128 data + 8 pad -> 272 B)

__device__ __forceinline__ unsigned short f2bf_rne(float f) {
  unsigned u = __builtin_bit_cast(unsigned, f);
  u += 0x7fffu + ((u >> 16) & 1u);
  return (unsigned short)(u >> 16);
}
__device__ __forceinline__ float bf2f(unsigned short s) {
  return __builtin_bit_cast(float, ((unsigned)s) << 16);
}
// pack two f32 -> two bf16 (truncate) in one v_perm_b32; lo short = p0
__device__ __forceinline__ unsigned pack_bf2(float p0, float p1) {
  return __builtin_amdgcn_perm(__builtin_bit_cast(unsigned, p1),
                               __builtin_bit_cast(unsigned, p0), 0x07060302u);
}

// ---- phase 1: M~[k][t] = sum_w wgt[w]*mix[w][k][t] -> bf16, 4-way w-split ----
__global__ __launch_bounds__(256) void prep_kernel(const float* __restrict__ mix,
                                                   const float* __restrict__ wgt,
                                                   unsigned short* __restrict__ Bp) {
  __shared__ float4 red[256];
  const int tid = threadIdx.x;
  const int ws  = tid >> 6;
  const int tt  = tid & 63;
  const int t4  = blockIdx.x * 64 + tt;
  const float4* m4 = (const float4*)mix;
  float ax = 0.f, ay = 0.f, az = 0.f, aw = 0.f;
#pragma unroll
  for (int wi = 0; wi < 8; ++wi) {
    const int w = ws * 8 + wi;
    const float s = wgt[w];
    const float4 v = m4[w * 65536 + t4];
    ax += s * v.x; ay += s * v.y; az += s * v.z; aw += s * v.w;
  }
  red[tid] = (float4){ax, ay, az, aw};
  __syncthreads();
  if (tid < 64) {
    const float4 a = red[tid], b = red[tid + 64], c = red[tid + 128], d = red[tid + 192];
    ushort4 r;
    r.x = f2bf_rne(a.x + b.x + c.x + d.x);
    r.y = f2bf_rne(a.y + b.y + c.y + d.y);
    r.z = f2bf_rne(a.z + b.z + c.z + d.z);
    r.w = f2bf_rne(a.w + b.w + c.w + d.w);
    ((ushort4*)Bp)[blockIdx.x * 64 + tid] = r;
  }
}

// ---- phase 1b: in-place symmetrize per k-slice.
// Bs[k,i,j] = M~[k,i,j]+M~[k,j,i] (i<j), M~[k,i,i] (diag), 0 (i>j).
// Each unordered pair (i<j) touched by exactly one thread -> race-free in place.
__global__ __launch_bounds__(256) void symm_kernel(unsigned short* __restrict__ Bp) {
  unsigned short* B = Bp + (size_t)blockIdx.x * 4096;  // one k per block
  for (int t = threadIdx.x; t < 4096; t += 256) {
    const int i = t >> 6, j = t & 63;
    if (i < j) {
      const int tt = (j << 6) | i;
      const float a = bf2f(B[t]);
      const float b = bf2f(B[tt]);
      B[t]  = f2bf_rne(a + b);
      B[tt] = 0;
    }
  }
}

// ---- phase 2: out[z][k] = sum_t V[z,t]*Bs[k,t], V generated in-register ----
// 256 threads (4 waves); wave owns 32 z (f=2); block = 128 z; grid 1024.
// Upper-triangular Bs: chunks c>=16 (i>=32) skip the h=0 (j<32) half exactly.
__global__ __launch_bounds__(256, 4) void gemm_kernel(const float* __restrict__ X,
                                                      const unsigned short* __restrict__ Bp,
                                                      float* __restrict__ out) {
  __shared__ unsigned short ldsB[2][64 * BROWS];  // [buf][k][128-t chunk]  34.8 KB
  __shared__ unsigned short sH[2][2][128];        // [buf][il][dword*2+half]  1 KB

  const int tid  = threadIdx.x;
  const int lane = tid & 63;
  const int wv   = tid >> 6;    // wave 0..3 -> z rows wv*32..+31
  const int m    = lane & 15;
  const int q    = lane >> 4;
  const int zblk = blockIdx.x * 128;

  // ---- stage B chunk 0 ----
#pragma unroll
  for (int it = 0; it < 4; ++it) {
    const int lin = tid + it * 256;  // 0..1023
    const int row = lin >> 4;        // k 0..63
    const int cc  = lin & 15;
    *(uint4*)(&ldsB[0][row * BROWS + cc * 8]) = *(const uint4*)(Bp + row * 4096 + cc * 8);
  }
  // ---- stage s chunk 0 (i = 0,1). dword d = wv*16+m holds
  // (x[zblk+wv*32+m, i] lo, x[zblk+wv*32+16+m, i] hi); writer thread t<128:
  // z_local = t = wv*32 + half*16 + m.
  if (tid < 128) {
    const float2 xp = *(const float2*)(X + (size_t)(zblk + tid) * 64);
    const int d  = (tid >> 5) * 16 + (tid & 15);
    const int hf = (tid >> 4) & 1;
    sH[0][0][d * 2 + hf] = f2bf_rne(xp.x);
    sH[0][1][d * 2 + hf] = f2bf_rne(xp.y);
  }

  // ---- per-lane fp32 j-cache: jv2[f][h*4+e] = {x[z(f,m), h*32+q*8+2e], x[..,+1]} ----
  v2f jv2[2][8];
  {
    const float4* X4g = (const float4*)X;
#pragma unroll
    for (int f = 0; f < 2; ++f) {
      const int zg = zblk + wv * 32 + f * 16 + m;
#pragma unroll
      for (int h = 0; h < 2; ++h) {
        const float4 a = X4g[zg * 16 + h * 8 + q * 2];
        const float4 b = X4g[zg * 16 + h * 8 + q * 2 + 1];
        jv2[f][h * 4 + 0] = v2f{a.x, a.y};
        jv2[f][h * 4 + 1] = v2f{a.z, a.w};
        jv2[f][h * 4 + 2] = v2f{b.x, b.y};
        jv2[f][h * 4 + 3] = v2f{b.z, b.w};
      }
    }
  }

  f32x4 acc[2][4];
#pragma unroll
  for (int f = 0; f < 2; ++f)
#pragma unroll
    for (int g = 0; g < 4; ++g) acc[f][g] = f32x4{0.f, 0.f, 0.f, 0.f};

  __syncthreads();

  auto chunk_body = [&](int c, bool full) {
    const int cn = (c + 1) & (NCHUNK - 1);
    // prefetch next B chunk global(L2) -> regs; published after the MFMA block
    uint4 pre[4];
#pragma unroll
    for (int it = 0; it < 4; ++it) {
      const int lin = tid + it * 256;
      const int row = lin >> 4;
      const int cc  = lin & 15;
      pre[it] = *(const uint4*)(Bp + row * 4096 + cn * 128 + cc * 8);
    }
    // prefetch next chunk's broadcast x[z, 2cn..2cn+1]
    float2 spre = {0.f, 0.f};
    if (tid < 128)
      spre = *(const float2*)(X + (size_t)(zblk + tid) * 64 + cn * 2);

    const unsigned short* Bl = ldsB[c & 1];
#pragma unroll
    for (int il = 0; il < 2; ++il) {
      const unsigned sv = *(const unsigned*)(&sH[c & 1][il][(wv * 16 + m) * 2]);
      const float s0 = __builtin_bit_cast(float, sv << 16);          // f=0: z=wv*32+m
      const float s1 = __builtin_bit_cast(float, sv & 0xffff0000u);  // f=1: z=wv*32+16+m
      auto hblk = [&](int h) {
        const unsigned short* bb = Bl + m * BROWS + il * 64 + h * 32 + q * 8;
        const short8 b0 = *(const short8*)(bb);
        const short8 b1 = *(const short8*)(bb + 16 * BROWS);
        const short8 b2 = *(const short8*)(bb + 32 * BROWS);
        const short8 b3 = *(const short8*)(bb + 48 * BROWS);
#pragma unroll
        for (int f = 0; f < 2; ++f) {
          const float sf_ = f ? s1 : s0;
          const v2f s2 = v2f{sf_, sf_};
          union { unsigned u[4]; short8 v; } A;
#pragma unroll
          for (int e = 0; e < 4; ++e) {
            const v2f pr = s2 * jv2[f][h * 4 + e];   // v_pk_mul_f32
            A.u[e] = pack_bf2(pr[0], pr[1]);
          }
          acc[f][0] = __builtin_amdgcn_mfma_f32_16x16x32_bf16(A.v, b0, acc[f][0], 0, 0, 0);
          acc[f][1] = __builtin_amdgcn_mfma_f32_16x16x32_bf16(A.v, b1, acc[f][1], 0, 0, 0);
          acc[f][2] = __builtin_amdgcn_mfma_f32_16x16x32_bf16(A.v, b2, acc[f][2], 0, 0, 0);
          acc[f][3] = __builtin_amdgcn_mfma_f32_16x16x32_bf16(A.v, b3, acc[f][3], 0, 0, 0);
        }
      };
      if (full) hblk(0);  // j<32 half: only needed while i<32 (Bs upper-triangular)
      hblk(1);
    }

    // publish prefetched chunk into the other buffers
    {
      unsigned short* dst = ldsB[(c + 1) & 1];
#pragma unroll
      for (int it = 0; it < 4; ++it) {
        const int lin = tid + it * 256;
        const int row = lin >> 4;
        const int cc  = lin & 15;
        *(uint4*)(&dst[row * BROWS + cc * 8]) = pre[it];
      }
      if (tid < 128) {
        const int d  = (tid >> 5) * 16 + (tid & 15);
        const int hf = (tid >> 4) & 1;
        sH[(c + 1) & 1][0][d * 2 + hf] = f2bf_rne(spre.x);
        sH[(c + 1) & 1][1][d * 2 + hf] = f2bf_rne(spre.y);
      }
    }
    __syncthreads();
  };

  for (int c = 0; c < 16; ++c)      chunk_body(c, true);   // i < 32: full
  for (int c = 16; c < NCHUNK; ++c) chunk_body(c, false);  // i >= 32: h=1 only

  // ---- epilogue: C/D layout col=lane&15 (k), row=q*4+r (z) ----
#pragma unroll
  for (int f = 0; f < 2; ++f) {
    const int zr = zblk + wv * 32 + f * 16 + q * 4;
#pragma unroll
    for (int g = 0; g < 4; ++g)
#pragma unroll
      for (int r = 0; r < 4; ++r)
        out[(size_t)(zr + r) * 64 + g * 16 + m] = acc[f][g][r];
  }
}

extern "C" void kernel_launch(void* const* d_in, const int* in_sizes, int n_in,
                              void* d_out, int out_size, void* d_ws, size_t ws_size,
                              hipStream_t stream) {
  const float* X   = (const float*)d_in[0];   // [131072, 64]
  const float* mix = (const float*)d_in[1];   // [32, 64, 64, 64]
  const float* wgt = (const float*)d_in[2];   // [32]
  float* out = (float*)d_out;                 // [131072, 64]
  unsigned short* Bp = (unsigned short*)d_ws; // 512 KB scratch: Bs bf16 [64][4096]

  prep_kernel<<<1024, 256, 0, stream>>>(mix, wgt, Bp);
  symm_kernel<<<64, 256, 0, stream>>>(Bp);
  gemm_kernel<<<1024, 256, 0, stream>>>(X, Bp, out);
}

// Round 2
// 160.999 us; speedup vs baseline: 1.5491x; 1.5491x over previous
//
#include <hip/hip_runtime.h>
#include <stdint.h>

typedef __attribute__((ext_vector_type(8))) short short8;
typedef __attribute__((ext_vector_type(4))) float f32x4;
typedef __attribute__((ext_vector_type(2))) float v2f;

#define NCHUNK 32     // 4096 t / 128 t per chunk (2 i-slices per chunk)

__device__ __forceinline__ unsigned short f2bf_rne(float f) {
  unsigned u = __builtin_bit_cast(unsigned, f);
  u += 0x7fffu + ((u >> 16) & 1u);
  return (unsigned short)(u >> 16);
}
__device__ __forceinline__ float bf2f(unsigned short s) {
  return __builtin_bit_cast(float, ((unsigned)s) << 16);
}
// pack two f32 -> two bf16 (truncate) in one v_perm_b32; lo short = p0
__device__ __forceinline__ unsigned pack_bf2(float p0, float p1) {
  return __builtin_amdgcn_perm(__builtin_bit_cast(unsigned, p1),
                               __builtin_bit_cast(unsigned, p0), 0x07060302u);
}
// async global->LDS, 16 B per lane; lds dest must be wave-uniform base
__device__ __forceinline__ void gload16(const void* g, void* l) {
  __builtin_amdgcn_global_load_lds((const __attribute__((address_space(1))) void*)g,
                                   (__attribute__((address_space(3))) void*)l, 16, 0, 0);
}

// ---- phase 1: M~[k][t] = sum_w wgt[w]*mix[w][k][t] -> bf16, 4-way w-split ----
__global__ __launch_bounds__(256) void prep_kernel(const float* __restrict__ mix,
                                                   const float* __restrict__ wgt,
                                                   unsigned short* __restrict__ Bp) {
  __shared__ float4 red[256];
  const int tid = threadIdx.x;
  const int ws  = tid >> 6;
  const int tt  = tid & 63;
  const int t4  = blockIdx.x * 64 + tt;
  const float4* m4 = (const float4*)mix;
  float ax = 0.f, ay = 0.f, az = 0.f, aw = 0.f;
#pragma unroll
  for (int wi = 0; wi < 8; ++wi) {
    const int w = ws * 8 + wi;
    const float s = wgt[w];
    const float4 v = m4[w * 65536 + t4];
    ax += s * v.x; ay += s * v.y; az += s * v.z; aw += s * v.w;
  }
  red[tid] = (float4){ax, ay, az, aw};
  __syncthreads();
  if (tid < 64) {
    const float4 a = red[tid], b = red[tid + 64], c = red[tid + 128], d = red[tid + 192];
    ushort4 r;
    r.x = f2bf_rne(a.x + b.x + c.x + d.x);
    r.y = f2bf_rne(a.y + b.y + c.y + d.y);
    r.z = f2bf_rne(a.z + b.z + c.z + d.z);
    r.w = f2bf_rne(a.w + b.w + c.w + d.w);
    ((ushort4*)Bp)[blockIdx.x * 64 + tid] = r;
  }
}

// ---- phase 1b: in-place symmetrize per k-slice.
// Bs[k,i,j] = M~[k,i,j]+M~[k,j,i] (i<j), M~[k,i,i] (diag), 0 (i>j).
__global__ __launch_bounds__(256) void symm_kernel(unsigned short* __restrict__ Bp) {
  unsigned short* B = Bp + (size_t)blockIdx.x * 4096;  // one k per block
  for (int t = threadIdx.x; t < 4096; t += 256) {
    const int i = t >> 6, j = t & 63;
    if (i < j) {
      const int tt = (j << 6) | i;
      const float a = bf2f(B[t]);
      const float b = bf2f(B[tt]);
      B[t]  = f2bf_rne(a + b);
      B[tt] = 0;
    }
  }
}

// ---- phase 2: out[z][k] = sum_t V[z,t]*Bs[k,t], V generated in-register ----
// 256 threads (4 waves); wave owns 32 z (f=2); block = 128 z; grid 1024.
// B staged via global_load_lds into linear [64][128] LDS with XOR-16B-unit
// swizzle (u' = u ^ (row&15)): linear dest + pre-swizzled global source +
// swizzled read address (rule: both-sides-or-neither).
// Upper-triangular Bs: chunks c>=16 (i>=32) skip the h=0 (j<32) half exactly.
__global__ __launch_bounds__(256, 3) void gemm_kernel(const float* __restrict__ X,
                                                      const unsigned short* __restrict__ Bp,
                                                      float* __restrict__ out) {
  __shared__ unsigned short ldsB[2][64 * 128];    // [buf][k][128-t chunk]  32 KB
  __shared__ unsigned short sH[2][2][128];        // [buf][il][dword*2+half] 1 KB

  const int tid  = threadIdx.x;
  const int lane = tid & 63;
  const int wv   = tid >> 6;    // wave 0..3 -> z rows wv*32..+31
  const int m    = lane & 15;
  const int q    = lane >> 4;
  const int zblk = blockIdx.x * 128;

  // stage chunk ct into ldsB[bf]: 4 waves x 4 iters x 1 KB segments.
  // segment s = wv*4+it covers rows 4s..4s+3; lane writes 16 B at dest+lane*16,
  // i.e. (row = 4s + lane/16, slot u' = lane&15); source unit u = u' ^ (row&15).
  auto stageB = [&](int ct, int bf) {
#pragma unroll
    for (int it = 0; it < 4; ++it) {
      const int row = wv * 16 + it * 4 + (lane >> 4);
      const int u   = (lane & 15) ^ (row & 15);
      gload16(Bp + (size_t)row * 4096 + ct * 128 + u * 8,
              &ldsB[bf][(wv * 4 + it) * 512]);
    }
  };

  // ---- prologue: B chunk 0 + s chunk 0 ----
  stageB(0, 0);
  if (tid < 128) {
    const float2 xp = *(const float2*)(X + (size_t)(zblk + tid) * 64);
    const int d  = (tid >> 5) * 16 + (tid & 15);
    const int hf = (tid >> 4) & 1;
    sH[0][0][d * 2 + hf] = f2bf_rne(xp.x);
    sH[0][1][d * 2 + hf] = f2bf_rne(xp.y);
  }

  // ---- per-lane fp32 j-cache: jv2[f][h*4+e] = {x[z(f,m), h*32+q*8+2e], x[..,+1]} ----
  v2f jv2[2][8];
  {
    const float4* X4g = (const float4*)X;
#pragma unroll
    for (int f = 0; f < 2; ++f) {
      const int zg = zblk + wv * 32 + f * 16 + m;
#pragma unroll
      for (int h = 0; h < 2; ++h) {
        const float4 a = X4g[zg * 16 + h * 8 + q * 2];
        const float4 b = X4g[zg * 16 + h * 8 + q * 2 + 1];
        jv2[f][h * 4 + 0] = v2f{a.x, a.y};
        jv2[f][h * 4 + 1] = v2f{a.z, a.w};
        jv2[f][h * 4 + 2] = v2f{b.x, b.y};
        jv2[f][h * 4 + 3] = v2f{b.z, b.w};
      }
    }
  }

  f32x4 acc[2][4];
#pragma unroll
  for (int f = 0; f < 2; ++f)
#pragma unroll
    for (int g = 0; g < 4; ++g) acc[f][g] = f32x4{0.f, 0.f, 0.f, 0.f};

  __syncthreads();

  auto chunk_body = [&](int c, bool full) {
    const int cn = (c + 1) & (NCHUNK - 1);
    // async-stage next B chunk (in flight across the MFMA block, drained at barrier)
    stageB(cn, (c + 1) & 1);
    // prefetch next chunk's broadcast x[z, 2cn..2cn+1]
    float2 spre = {0.f, 0.f};
    if (tid < 128)
      spre = *(const float2*)(X + (size_t)(zblk + tid) * 64 + cn * 2);

    const unsigned short* Bl = &ldsB[c & 1][0];
#pragma unroll
    for (int il = 0; il < 2; ++il) {
      const unsigned sv = *(const unsigned*)(&sH[c & 1][il][(wv * 16 + m) * 2]);
      const float s0 = __builtin_bit_cast(float, sv << 16);          // f=0: z=wv*32+m
      const float s1 = __builtin_bit_cast(float, sv & 0xffff0000u);  // f=1: z=wv*32+16+m
      auto hblk = [&](int h) {
        const int u = ((il << 3) + (h << 2) + q) ^ m;   // swizzled 16B unit
        const unsigned short* bb = Bl + m * 128 + u * 8;
        const short8 b0 = *(const short8*)(bb);
        const short8 b1 = *(const short8*)(bb + 16 * 128);
        const short8 b2 = *(const short8*)(bb + 32 * 128);
        const short8 b3 = *(const short8*)(bb + 48 * 128);
#pragma unroll
        for (int f = 0; f < 2; ++f) {
          const float sf_ = f ? s1 : s0;
          const v2f s2 = v2f{sf_, sf_};
          union { unsigned u[4]; short8 v; } A;
#pragma unroll
          for (int e = 0; e < 4; ++e) {
            const v2f pr = s2 * jv2[f][h * 4 + e];   // v_pk_mul_f32
            A.u[e] = pack_bf2(pr[0], pr[1]);
          }
          acc[f][0] = __builtin_amdgcn_mfma_f32_16x16x32_bf16(A.v, b0, acc[f][0], 0, 0, 0);
          acc[f][1] = __builtin_amdgcn_mfma_f32_16x16x32_bf16(A.v, b1, acc[f][1], 0, 0, 0);
          acc[f][2] = __builtin_amdgcn_mfma_f32_16x16x32_bf16(A.v, b2, acc[f][2], 0, 0, 0);
          acc[f][3] = __builtin_amdgcn_mfma_f32_16x16x32_bf16(A.v, b3, acc[f][3], 0, 0, 0);
        }
      };
      if (full) hblk(0);  // j<32 half: only needed while i<32 (Bs upper-triangular)
      hblk(1);
    }

    // publish next chunk's s-broadcast
    if (tid < 128) {
      const int d  = (tid >> 5) * 16 + (tid & 15);
      const int hf = (tid >> 4) & 1;
      sH[(c + 1) & 1][0][d * 2 + hf] = f2bf_rne(spre.x);
      sH[(c + 1) & 1][1][d * 2 + hf] = f2bf_rne(spre.y);
    }
    __syncthreads();   // drains vmcnt -> staged B chunk visible
  };

  for (int c = 0; c < 16; ++c)      chunk_body(c, true);   // i < 32: full
  for (int c = 16; c < NCHUNK; ++c) chunk_body(c, false);  // i >= 32: h=1 only

  // ---- epilogue: C/D layout col=lane&15 (k), row=q*4+r (z) ----
#pragma unroll
  for (int f = 0; f < 2; ++f) {
    const int zr = zblk + wv * 32 + f * 16 + q * 4;
#pragma unroll
    for (int g = 0; g < 4; ++g)
#pragma unroll
      for (int r = 0; r < 4; ++r)
        out[(size_t)(zr + r) * 64 + g * 16 + m] = acc[f][g][r];
  }
}

extern "C" void kernel_launch(void* const* d_in, const int* in_sizes, int n_in,
                              void* d_out, int out_size, void* d_ws, size_t ws_size,
                              hipStream_t stream) {
  const float* X   = (const float*)d_in[0];   // [131072, 64]
  const float* mix = (const float*)d_in[1];   // [32, 64, 64, 64]
  const float* wgt = (const float*)d_in[2];   // [32]
  float* out = (float*)d_out;                 // [131072, 64]
  unsigned short* Bp = (unsigned short*)d_ws; // 512 KB scratch: Bs bf16 [64][4096]

  prep_kernel<<<1024, 256, 0, stream>>>(mix, wgt, Bp);
  symm_kernel<<<64, 256, 0, stream>>>(Bp);
  gemm_kernel<<<1024, 256, 0, stream>>>(X, Bp, out);
}